// Round 2
// baseline (108.323 us; speedup 1.0000x reference)
//
#include <hip/hip_runtime.h>

// out[b,m,d,f] = sum_{a,c} x[b,m,a,f] * y[b,m,c,f] * cgc[a,d,c]
// Round 8 (= R7 + compile fix): barrier-free, LDS-free direct-load structure,
// packed-fp16 P build.
//
// Per bm: out[16,128] = W[16,256] . P[256,128], k = a*16+c,
//   W[d,k] = cgc[a,d,c]  (A-frags, same verified quad->(qh,c0) k-mapping as R3-R6)
//   P[k,f] = x[a,f]*y[c,f], built in-register as packed fp16 (v_pk_mul_f16).
//
// Structure: one wave owns one bm (4096 waves = 1024 blocks x 4 waves).
// Wave loops over 4 f-groups of 32 columns; per group it direct-loads its
// column slices from global (each load = 2x64B segments; every 128B line is
// consumed entirely by exactly one wave -> zero over-fetch), packs to fp16,
// runs 16 MFMAs, stores. Next group's loads issue right after repack, so HBM
// latency hides under compute + 16-wave TLP. No __syncthreads, no LDS, no
// vmcnt(0) convoy: pure streaming at BW limit.

typedef __attribute__((ext_vector_type(2))) _Float16 half2v;
typedef __attribute__((ext_vector_type(8))) _Float16 half8;
typedef __attribute__((ext_vector_type(4))) float    floatx4;

#define AA 16
#define FF 128

union H8 { half2v h2[4]; half8 h8; };

// cvt_pkrtz returns a __fp16 ext-vector; bit-cast to the _Float16 vector type
// so downstream arithmetic stays native packed-half (v_pk_mul_f16).
static __device__ __forceinline__ half2v pkrtz(float a, float b) {
    return __builtin_bit_cast(half2v, __builtin_amdgcn_cvt_pkrtz(a, b));
}

__global__ __launch_bounds__(256, 4)
void tpc_mfma_direct_kernel(const float* __restrict__ x,
                            const float* __restrict__ y,
                            const float* __restrict__ cgc,
                            float* __restrict__ out) {
    const int tid  = threadIdx.x;
    const int w    = tid >> 6;         // wave 0..3
    const int lane = tid & 63;
    const int L    = lane & 15;        // A: m(=d); B: n(=f within tile); D: col
    const int quad = lane >> 4;
    const int qh   = quad >> 1;        // a parity
    const int c0   = (quad & 1) * 8;   // c sub-range

    const int bm = blockIdx.x * 4 + w; // one bm per wave, 4096 total
    const size_t stride = (size_t)(AA * FF);
    const float* xb = x + (size_t)bm * stride;
    const float* yb = y + (size_t)bm * stride;
    float*       ob = out + (size_t)bm * stride;

    // ---- issue group-0 x/y column loads first (HBM, longest latency) ----
    float xA[8], xB[8], yA[8], yB[8];
#pragma unroll
    for (int t = 0; t < 8; ++t) {
        xA[t] = xb[(2 * t + qh) * FF + L];
        xB[t] = xb[(2 * t + qh) * FF + L + 16];
    }
#pragma unroll
    for (int j = 0; j < 8; ++j) {
        yA[j] = yb[(c0 + j) * FF + L];
        yB[j] = yb[(c0 + j) * FF + L + 16];
    }

    // ---- W fragments (fp16) from cgc: L2-resident, latency hides under the
    //      group-0 HBM loads. ----
    half8 wfrag[8];
#pragma unroll
    for (int t = 0; t < 8; ++t) {
        const float* wp = cgc + (2 * t + qh) * (AA * AA) + L * AA + c0;
        const floatx4 w0 = *(const floatx4*)(wp);
        const floatx4 w1 = *(const floatx4*)(wp + 4);
        H8 wa;
        wa.h2[0] = pkrtz(w0.x, w0.y);
        wa.h2[1] = pkrtz(w0.z, w0.w);
        wa.h2[2] = pkrtz(w1.x, w1.y);
        wa.h2[3] = pkrtz(w1.z, w1.w);
        wfrag[t] = wa.h8;
    }

    for (int g = 0; g < 4; ++g) {
        // ---- pack current group's columns to fp16 (consumes raw regs) ----
        half2v yp0[4], yp1[4];
#pragma unroll
        for (int jj = 0; jj < 4; ++jj) {
            yp0[jj] = pkrtz(yA[2 * jj], yA[2 * jj + 1]);
            yp1[jj] = pkrtz(yB[2 * jj], yB[2 * jj + 1]);
        }
        half2v xp0[8], xp1[8];
#pragma unroll
        for (int t = 0; t < 8; ++t) {
            xp0[t] = pkrtz(xA[t], xA[t]);
            xp1[t] = pkrtz(xB[t], xB[t]);
        }

        // ---- raw regs free: issue next group's loads now; the 16 MFMAs +
        //      packing below cover most of their latency ----
        if (g < 3) {
            const int fA = (g + 1) * 32 + L;
#pragma unroll
            for (int t = 0; t < 8; ++t) {
                xA[t] = xb[(2 * t + qh) * FF + fA];
                xB[t] = xb[(2 * t + qh) * FF + fA + 16];
            }
#pragma unroll
            for (int j = 0; j < 8; ++j) {
                yA[j] = yb[(c0 + j) * FF + fA];
                yB[j] = yb[(c0 + j) * FF + fA + 16];
            }
        }

        // ---- MFMA over k=256 for f-tiles (2g, 2g+1) ----
        floatx4 acc0 = {0.f, 0.f, 0.f, 0.f};
        floatx4 acc1 = {0.f, 0.f, 0.f, 0.f};
#pragma unroll
        for (int t = 0; t < 8; ++t) {
            H8 b0;
            b0.h2[0] = xp0[t] * yp0[0];
            b0.h2[1] = xp0[t] * yp0[1];
            b0.h2[2] = xp0[t] * yp0[2];
            b0.h2[3] = xp0[t] * yp0[3];
            acc0 = __builtin_amdgcn_mfma_f32_16x16x32_f16(wfrag[t], b0.h8, acc0, 0, 0, 0);

            H8 b1;
            b1.h2[0] = xp1[t] * yp1[0];
            b1.h2[1] = xp1[t] * yp1[1];
            b1.h2[2] = xp1[t] * yp1[2];
            b1.h2[3] = xp1[t] * yp1[3];
            acc1 = __builtin_amdgcn_mfma_f32_16x16x32_f16(wfrag[t], b1.h8, acc1, 0, 0, 0);
        }

        // ---- stores: 4 rows x 2 tiles, 64B-coalesced per 16-lane quad ----
        const int f0 = g * 32 + L;
#pragma unroll
        for (int r = 0; r < 4; ++r) {
            const int row = (quad * 4 + r) * FF;
            ob[row + f0]      = acc0[r];
            ob[row + f0 + 16] = acc1[r];
        }
    }
}

extern "C" void kernel_launch(void* const* d_in, const int* in_sizes, int n_in,
                              void* d_out, int out_size, void* d_ws, size_t ws_size,
                              hipStream_t stream) {
    const float* x   = (const float*)d_in[0];
    const float* y   = (const float*)d_in[1];
    const float* cgc = (const float*)d_in[2];
    float* out = (float*)d_out;

    // 4096 bm, one per wave: 1024 blocks x 256 threads (4 waves each).
    hipLaunchKernelGGL(tpc_mfma_direct_kernel, dim3(1024), dim3(256), 0, stream,
                       x, y, cgc, out);
}